// Round 6
// baseline (266.933 us; speedup 1.0000x reference)
//
#include <hip/hip_runtime.h>
#include <math.h>

// STFT: inputs [64, 262144] f32, frame_length=8, frame_step=4, periodic Hann.
// num_frames = (262144-8)/4 + 1 = 65535, bins = 5.
// out = concat(magnitude[64,5,65535], phase[64,5,65535]) flat f32.
//
// R6 = R5 (dense interleaved stores, proven passing) + non-temporal output
// stores. Output is write-once/never-read: nt keeps the 168 MB stream from
// thrashing the 32 MB L2 and leaves the (L3-resident) input cached.
// Compute path bit-identical to R4/R5 (absmax 0.015625).

#define B 64
#define T 262144
#define NUM_FRAMES 65535
#define BINS 5

__global__ __launch_bounds__(256) void stft_kernel(const float* __restrict__ in,
                                                   float* __restrict__ out) {
    const int lane = threadIdx.x & 63;
    const int wave = (blockIdx.x * 256 + threadIdx.x) >> 6;  // 0..255 per row
    const int b = blockIdx.y;

    const float* __restrict__ row = in + (size_t)b * T;
    const size_t plane = (size_t)NUM_FRAMES;
    float* __restrict__ magb = out + (size_t)b * BINS * plane;
    float* __restrict__ phb  = magb + (size_t)B * BINS * plane;

    const float w1 = 0.14644660940672624f;  // 0.5 - 0.5*cos(pi/4)
    const float w3 = 0.85355339059327376f;  // 0.5 - 0.5*cos(3pi/4)
    const float c  = 0.70710678118654752f;  // sqrt(2)/2

#pragma unroll
    for (int g = 0; g < 4; ++g) {
        const int f = wave * 256 + g * 64 + lane;          // frame index
        const int fl = (f < NUM_FRAMES) ? f : (NUM_FRAMES - 1);  // clamp load only

        // Frame fl starts at sample 4*fl (16 B aligned): two aligned float4.
        const float4 lo = *(const float4*)(row + 4 * fl);
        const float4 hi = *(const float4*)(row + 4 * fl + 4);

        const float x1 = lo.y * w1;
        const float x2 = lo.z * 0.5f;
        const float x3 = lo.w * w3;
        const float x4 = hi.x;          // w=1; lo.x has w=0
        const float x5 = hi.y * w3;
        const float x6 = hi.z * 0.5f;
        const float x7 = hi.w * w1;

        const float s1  = x1 - x3 - x5 + x7;
        const float s2  = x1 + x3 - x5 - x7;
        const float d26 = x2 - x6;

        const float re0 = x1 + x2 + x3 + x4 + x5 + x6 + x7;
        const float re1 = -x4 + c * s1;
        const float im1 = -c * s2 - d26;
        const float re2 = -x2 + x4 - x6;
        const float im2 = -(x1 - x3 + x5 - x7);
        const float re3 = -x4 - c * s1;
        const float im3 = -c * s2 + d26;
        const float re4 = -x1 + x2 - x3 + x4 - x5 + x6 - x7;

        if (f < NUM_FRAMES) {   // only global frame 65535 is invalid
            __builtin_nontemporal_store(__builtin_fabsf(re0), &magb[0 * plane + f]);
            __builtin_nontemporal_store(__builtin_amdgcn_sqrtf(fmaf(re1, re1, im1 * im1)), &magb[1 * plane + f]);
            __builtin_nontemporal_store(__builtin_amdgcn_sqrtf(fmaf(re2, re2, im2 * im2)), &magb[2 * plane + f]);
            __builtin_nontemporal_store(__builtin_amdgcn_sqrtf(fmaf(re3, re3, im3 * im3)), &magb[3 * plane + f]);
            __builtin_nontemporal_store(__builtin_fabsf(re4), &magb[4 * plane + f]);

            __builtin_nontemporal_store(atan2f(0.0f, re0), &phb[0 * plane + f]);
            __builtin_nontemporal_store(atan2f(im1, re1), &phb[1 * plane + f]);
            __builtin_nontemporal_store(atan2f(im2, re2), &phb[2 * plane + f]);
            __builtin_nontemporal_store(atan2f(im3, re3), &phb[3 * plane + f]);
            __builtin_nontemporal_store(atan2f(0.0f, re4), &phb[4 * plane + f]);
        }
    }
}

extern "C" void kernel_launch(void* const* d_in, const int* in_sizes, int n_in,
                              void* d_out, int out_size, void* d_ws, size_t ws_size,
                              hipStream_t stream) {
    (void)in_sizes; (void)n_in; (void)d_ws; (void)ws_size; (void)out_size;
    const float* in = (const float*)d_in[0];
    float* out = (float*)d_out;

    dim3 block(256);
    dim3 grid(64, B);   // 64 blocks/row x 64 rows; 256 waves/row x 256 frames/wave
    stft_kernel<<<grid, block, 0, stream>>>(in, out);
}